// Round 16
// baseline (218.289 us; speedup 1.0000x reference)
//
#include <hip/hip_runtime.h>
#include <hip/hip_bf16.h>

// DepConv3D R16 — producer/consumer structure at 2 blocks/CU.
//   diff = depth[nbr]-depth[center]; kd=0 iff diff==-1, kd=1 iff diff==0, else 0.
// R15 isolated the fused kernel at 77.8 us vs ~30 us for perfectly-overlapped
// ablation parts (R12). Last untested cell: wave-specialization x TWO
// independent barrier domains per CU. R9 ran 1 block/CU, so each of its 8
// __syncthreads idles the whole CU on the straggler phase. R16 halves the
// tile (2 rows x 128 px), NT=8, 384 threads = 4 consumer + 2 producer waves,
// LDS 45.8 KB -> grid 512 = 2 blocks/CU (same 12 waves/CU, two pipelines):
// block A's barrier-wait overlaps block B's compute.
// All validated machinery from R9: producer stage (clamped loads, SENT
// sentinel, v_cvt_pk packing, 40 B padded px stride -> conflict-free b64),
// consumer MFMA body (feat=A/wgt=B 16x16x32_bf16, 1st op m=lane&15,
// kk=(lane>>4)*8+j; D col=lane&15=oc, row=(lane>>4)*4+r=pixel -> dwordx4).
// __launch_bounds__(384,2): cap 128 (R2's hard-cap-64 spill avoided).
// Falsifier: fused >= 75 us => interference is pipe-level; R9 is final.

#define IC 16
#define OC 32
#define Hh 512
#define Ww 512
#define HW (Hh * Ww)
#define TW 128          // tile width  (output px)
#define TR 2            // tile rows   (output)
#define PXS 20          // shorts per px in LDS (40 B, padded from 32)
#define SENT (1 << 20)  // sentinel depth: diff never in {0,-1}
#define NT 8            // tiles per block; 4096 tiles / 8 = 512 blocks

typedef __attribute__((ext_vector_type(8))) short short8;
typedef __attribute__((ext_vector_type(4))) float float4v;
typedef __attribute__((ext_vector_type(2))) unsigned int uint2v;

__device__ __forceinline__ unsigned short f2bf(float x) {
    unsigned u = __float_as_uint(x);
    unsigned r = u + 0x7FFFu + ((u >> 16) & 1u);   // RNE
    return (unsigned short)(r >> 16);
}

// packed RNE pair via v_cvt_pk_bf16_f32 (compiler fuses _rn cast pairs)
__device__ __forceinline__ unsigned packbf(float a, float b) {
    union { __hip_bfloat162 h2; unsigned u; } cv;
    cv.h2 = __float22bfloat162_rn(make_float2(a, b));
    return cv.u;
}

// ---- prepass: fp32 weights (32,16,3,3,3) -> bf16 fragments (2nd-operand) ----
__global__ void prep_weights(const float* __restrict__ wgt,
                             unsigned short* __restrict__ wsA) {
    int e = blockIdx.x * 256 + threadIdx.x;
    if (e >= 9 * 2 * 64 * 8) return;
    int j    = e & 7;
    int lane = (e >> 3) & 63;
    int mt   = (e >> 9) & 1;
    int c    = e >> 10;
    int oc = mt * 16 + (lane & 15);
    int kk = ((lane >> 4) << 3) + j;
    wsA[e] = f2bf(wgt[oc * 432 + (kk >> 1) * 27 + (kk & 1) * 9 + c]);
}

// ---- fused main kernel: producer/consumer waves, 2 blocks/CU ----
__global__ __launch_bounds__(384, 2) void depconv_fused(
    const float* __restrict__ feat,           // (4,16,512,512) fp32
    const int*   __restrict__ depth,          // (4,512,512)
    const unsigned short* __restrict__ wsA,
    float*       __restrict__ out)            // (4,32,512,512)
{
    __shared__ unsigned short ftile[2][TR + 2][TW + 2][PXS];  // 41,600 B
    __shared__ int            dtile[2][TR + 2][TW + 2];       //  4,160 B

    const int tid = threadIdx.x;
    const int bid = blockIdx.x;
    // XCD bijective swizzle: 512 blocks, 8 XCDs
    const int wg = (bid & 7) * 64 + (bid >> 3);
    const int t0 = wg * NT;
    // tile tt: b = tt>>10, rowpair = (tt>>2)&255, colblk = tt&3

    const bool isProd = (tid >= 256);
    const int  xl     = tid - 256;     // producer: body px [0,128)

    // consumer roles (garbage-but-unused for producer threads)
    const int lane = tid & 63;
    const int wv   = tid >> 6;
    const int g    = lane >> 4;        // ic-group for A-build: ics 4g..4g+3
    const int n    = lane & 15;        // A-operand pixel (m = lane&15)
    const int rr   = wv >> 1;          // output row within tile: 0..1
    const int xoff = (wv & 1) * 64;
    const int q    = lane >> 4;        // store: pixel quad 4q..4q+3
    const int oc0  = lane & 15;        // store: oc plane

    // weight fragments (consumers only; loads overlap producer prologue)
    short8 wfrag[9][2];
    if (!isProd) {
        const short8* ap = (const short8*)wsA;
#pragma unroll
        for (int c = 0; c < 9; ++c) {
            wfrag[c][0] = ap[(c * 2 + 0) * 64 + lane];
            wfrag[c][1] = ap[(c * 2 + 1) * 64 + lane];
        }
    }

    // ---- producer: load + convert + LDS-write tile tt into buf p ----
    auto stage = [&](int p, int tt) {
        const int b      = tt >> 10;
        const int h0     = ((tt >> 2) & 255) * TR;
        const int wstart = (tt & 3) * TW;
        const int x   = wstart - 1 + xl;
        const bool xin = (unsigned)x < (unsigned)Ww;
        const int xc  = x < 0 ? 0 : (x > Ww - 1 ? Ww - 1 : x);
        const float* fb  = feat + (size_t)b * IC * HW + xc;
        const int*   dbp = depth + (b << 18) + xc;
#pragma unroll
        for (int r = 0; r < TR + 2; ++r) {
            const int y = h0 - 1 + r;
            const bool yin = (unsigned)y < (unsigned)Hh;
            const int yc = y < 0 ? 0 : (y > Hh - 1 ? Hh - 1 : y);
            const float* fpl = fb + (size_t)yc * Ww;
            dtile[p][r][xl] = (yin & xin) ? dbp[yc * Ww] : SENT;
            unsigned pk[8];
#pragma unroll
            for (int i = 0; i < 8; ++i)
                pk[i] = packbf(fpl[(size_t)(2 * i) * HW],
                               fpl[(size_t)(2 * i + 1) * HW]);
            unsigned short* wp = &ftile[p][r][xl][0];
            *(uint2v*)(wp)      = (uint2v){pk[0], pk[1]};
            *(uint2v*)(wp + 4)  = (uint2v){pk[2], pk[3]};
            *(uint2v*)(wp + 8)  = (uint2v){pk[4], pk[5]};
            *(uint2v*)(wp + 12) = (uint2v){pk[6], pk[7]};
        }
        // tail px 128,129: 8 threads, one (row, px) pair each
        if ((unsigned)xl < 8u) {
            const int r  = xl >> 1;
            const int tp = xl & 1;
            const int xt = wstart - 1 + TW + tp;
            const bool xtin = (unsigned)xt < (unsigned)Ww;
            const int xct = xt > Ww - 1 ? Ww - 1 : xt;
            const int y = h0 - 1 + r;
            const bool yin = (unsigned)y < (unsigned)Hh;
            const int yc = y < 0 ? 0 : (y > Hh - 1 ? Hh - 1 : y);
            const float* fpl = feat + (size_t)b * IC * HW + (size_t)yc * Ww + xct;
            dtile[p][r][TW + tp] = (yin & xtin) ? depth[(b << 18) + yc * Ww + xct]
                                                : SENT;
            unsigned qk[8];
#pragma unroll
            for (int i = 0; i < 8; ++i)
                qk[i] = packbf(fpl[(size_t)(2 * i) * HW],
                               fpl[(size_t)(2 * i + 1) * HW]);
            unsigned short* wq = &ftile[p][r][TW + tp][0];
            *(uint2v*)(wq)      = (uint2v){qk[0], qk[1]};
            *(uint2v*)(wq + 4)  = (uint2v){qk[2], qk[3]};
            *(uint2v*)(wq + 8)  = (uint2v){qk[4], qk[5]};
            *(uint2v*)(wq + 12) = (uint2v){qk[6], qk[7]};
        }
    };

    // ---- consumer: compute tile tt from buf p ----
    auto compute = [&](int p, int tt) {
        const int b      = tt >> 10;
        const int h0     = ((tt >> 2) & 255) * TR;
        const int wstart = (tt & 3) * TW;
        const int h = h0 + rr;
        float* opb0 = out + ((size_t)(b * OC + oc0) << 18) + (size_t)h * Ww;
#pragma unroll 1
        for (int it = 0; it < 4; ++it) {
            const int xb = xoff + it * 16 + n;
            const int dc = dtile[p][rr + 1][xb + 1];
            float4v acc0 = {0.f, 0.f, 0.f, 0.f};
            float4v acc1 = {0.f, 0.f, 0.f, 0.f};
#pragma unroll
            for (int t = 0; t < 9; ++t) {
                const int kh = t / 3, kw = t % 3;
                unsigned mm;
                if (t == 4) {
                    mm = 0xffff0000u;   // center: diff==0 always, kd=1 slice
                } else {
                    const int diff = dtile[p][rr + kh][xb + kw] - dc;
                    mm = (diff == 0) ? 0xffff0000u : ((diff == -1) ? 0x0000ffffu : 0u);
                }
                const uint2v pr = *(const uint2v*)(&ftile[p][rr + kh][xb + kw][g << 2]);
                union { short8 s; unsigned u[4]; } bf;
                bf.u[0] = __builtin_amdgcn_perm(0u, pr.x, 0x01000100u) & mm;  // ic 4g+0
                bf.u[1] = __builtin_amdgcn_perm(0u, pr.x, 0x03020302u) & mm;  // ic 4g+1
                bf.u[2] = __builtin_amdgcn_perm(0u, pr.y, 0x01000100u) & mm;  // ic 4g+2
                bf.u[3] = __builtin_amdgcn_perm(0u, pr.y, 0x03020302u) & mm;  // ic 4g+3

                // features as A (M=pixels), weights as B (N=oc)
                acc0 = __builtin_amdgcn_mfma_f32_16x16x32_bf16(bf.s, wfrag[t][0], acc0, 0, 0, 0);
                acc1 = __builtin_amdgcn_mfma_f32_16x16x32_bf16(bf.s, wfrag[t][1], acc1, 0, 0, 0);
            }
            // lane stores px w16+4q..+3 of plane oc0 (acc0) / oc0+16 (acc1)
            const int w16 = wstart + xoff + it * 16;
            float* op = opb0 + (w16 + 4 * q);
            *(float4v*)op                     = acc0;
            *(float4v*)(op + (size_t)16 * HW) = acc1;
        }
    };

    // ---- pipelined main loop: producers one tile ahead of consumers ----
    if (isProd) stage(0, t0);
    __syncthreads();
#pragma unroll 1
    for (int i = 0; i < NT; ++i) {
        if (!isProd) {
            compute(i & 1, t0 + i);
        } else if (i + 1 < NT) {
            stage((i + 1) & 1, t0 + i + 1);
        }
        __syncthreads();
    }
}

extern "C" void kernel_launch(void* const* d_in, const int* in_sizes, int n_in,
                              void* d_out, int out_size, void* d_ws, size_t ws_size,
                              hipStream_t stream) {
    const float* feat  = (const float*)d_in[0];
    const int*   depth = (const int*)d_in[1];
    const float* wgt   = (const float*)d_in[2];
    float* out = (float*)d_out;

    unsigned short* wsA = (unsigned short*)d_ws;     // 18,432 B only

    prep_weights<<<36, 256, 0, stream>>>(wgt, wsA);
    depconv_fused<<<512, 384, 0, stream>>>(feat, depth, wsA, out);
}

// Round 17
// 209.882 us; speedup vs baseline: 1.0401x; 1.0401x over previous
//
#include <hip/hip_runtime.h>
#include <hip/hip_bf16.h>

// DepConv3D — FINAL (R17 = R9/R15 verbatim; session best, reproduced twice:
// 209.3 / 209.5 us total, fused kernel ~78-85 us, passed, absmax 0.0156).
//   diff = depth[nbr]-depth[center]; kd=0 iff diff==-1, kd=1 iff diff==0, else 0.
// Producer/consumer wave-specialized: 256 blocks (1/CU), NT=4 tiles each,
// double-buffered 2x68 KB LDS; 768 threads = 8 consumer waves + 4 producer
// waves. While consumers compute tile i from LDS buf[i&1], producers
// load+convert+ds_write tile i+1 into buf[i^1]; producer load latency is
// hidden by co-resident consumer MFMA waves.
// Tile = 4 rows x 256 px, staged as 6x258 halo (bf16 pixel-major, 40 B padded
// px stride -> conflict-free b64 LDS; int depth with SENT for out-of-image).
// MFMA 16x16x32_bf16 (validated): 1st op m=lane&15, kk=(lane>>4)*8+j;
// D: col=lane&15 (oc), row=(lane>>4)*4+r (pixel) -> dwordx4 stores.
//
// SESSION CONCLUSION (R0-R16, full structure matrix tested):
//   - graded total = ~80-95 us workspace re-poison fill + ~45-55 us harness
//     cost + kernel chain (~87 us here). Only the chain is controllable.
//   - R12 ablation: stage-only ~22 us, compute+store-only ~22 us, combined
//     kernel 78-110 us across SIX structurally distinct schedules. The
//     VMEM-staging x LDS/MFMA-compute interaction costs ~4x the parts.
//   - falsified levers: VALU cuts (R4), occupancy (R5), VMEM-instr cuts
//     (R6), register prefetch (R7/R8 - allocator sinks it), weights-in-LDS
//     (R10), loop interchange (R11), DMA+counted-vmcnt async (R14),
//     2 barrier domains/CU (R16). Wave specialization (R9) is the one win.
//   - counters at the plateau: MfmaUtil ~9%, VALUBusy ~22%, HBM ~32% — an
//     interaction plateau at HIP source level, not a hardware roofline.

#define IC 16
#define OC 32
#define Hh 512
#define Ww 512
#define HW (Hh * Ww)
#define TW 256          // tile width  (output px)
#define TR 4            // tile rows   (output)
#define PXS 20          // shorts per px in LDS (40 B, padded from 32)
#define SENT (1 << 20)  // sentinel depth: diff never in {0,-1}
#define NT 4            // tiles per block; grid = 1024/NT = 256

typedef __attribute__((ext_vector_type(8))) short short8;
typedef __attribute__((ext_vector_type(4))) float float4v;
typedef __attribute__((ext_vector_type(2))) unsigned int uint2v;

__device__ __forceinline__ unsigned short f2bf(float x) {
    unsigned u = __float_as_uint(x);
    unsigned r = u + 0x7FFFu + ((u >> 16) & 1u);   // RNE
    return (unsigned short)(r >> 16);
}

// packed RNE pair via v_cvt_pk_bf16_f32 (compiler fuses _rn cast pairs)
__device__ __forceinline__ unsigned packbf(float a, float b) {
    union { __hip_bfloat162 h2; unsigned u; } cv;
    cv.h2 = __float22bfloat162_rn(make_float2(a, b));
    return cv.u;
}

// ---- prepass: fp32 weights (32,16,3,3,3) -> bf16 fragments (2nd-operand) ----
__global__ void prep_weights(const float* __restrict__ wgt,
                             unsigned short* __restrict__ wsA) {
    int e = blockIdx.x * 256 + threadIdx.x;
    if (e >= 9 * 2 * 64 * 8) return;
    int j    = e & 7;
    int lane = (e >> 3) & 63;
    int mt   = (e >> 9) & 1;
    int c    = e >> 10;
    int oc = mt * 16 + (lane & 15);
    int kk = ((lane >> 4) << 3) + j;
    wsA[e] = f2bf(wgt[oc * 432 + (kk >> 1) * 27 + (kk & 1) * 9 + c]);
}

// ---- fused main kernel: producer/consumer waves, double-buffered LDS ----
__global__ __launch_bounds__(768, 1) void depconv_fused(
    const float* __restrict__ feat,           // (4,16,512,512) fp32
    const int*   __restrict__ depth,          // (4,512,512)
    const unsigned short* __restrict__ wsA,
    float*       __restrict__ out)            // (4,32,512,512)
{
    __shared__ unsigned short ftile[2][6][TW + 2][PXS];   // 123,840 B
    __shared__ int            dtile[2][6][TW + 2];        //  12,384 B

    const int tid = threadIdx.x;
    const int bid = blockIdx.x;
    // XCD swizzle: 256 blocks, 8 XCDs -> XCD x gets contiguous wg [32x,32x+31]
    const int wg = (bid & 7) * 32 + (bid >> 3);
    const int t0 = wg * NT;

    const bool isProd = (tid >= 512);
    const int  xl     = tid - 512;     // producer: body px [0,256)

    // consumer roles (garbage-but-unused for producer threads)
    const int lane = tid & 63;
    const int wv   = tid >> 6;
    const int g    = lane >> 4;        // ic-group for A-build: ics 4g..4g+3
    const int n    = lane & 15;        // A-operand pixel (m = lane&15)
    const int rr   = wv >> 1;          // output row within tile: 0..3
    const int xoff = (wv & 1) * 128;
    const int q    = lane >> 4;        // store: pixel quad 4q..4q+3
    const int oc0  = lane & 15;        // store: oc plane

    // weight fragments (consumers only; loads overlap producer prologue)
    short8 wfrag[9][2];
    if (!isProd) {
        const short8* ap = (const short8*)wsA;
#pragma unroll
        for (int c = 0; c < 9; ++c) {
            wfrag[c][0] = ap[(c * 2 + 0) * 64 + lane];
            wfrag[c][1] = ap[(c * 2 + 1) * 64 + lane];
        }
    }

    // ---- producer: load + convert + LDS-write tile tt into buf p ----
    auto stage = [&](int p, int tt) {
        const int b      = tt >> 8;
        const int h0     = ((tt >> 1) & 127) * TR;
        const int wstart = (tt & 1) * TW;
        const int x   = wstart - 1 + xl;
        const bool xin = (unsigned)x < (unsigned)Ww;
        const int xc  = x < 0 ? 0 : (x > Ww - 1 ? Ww - 1 : x);
        const float* fb  = feat + (size_t)b * IC * HW + xc;
        const int*   dbp = depth + (b << 18) + xc;
#pragma unroll
        for (int r = 0; r < 6; ++r) {
            const int y = h0 - 1 + r;
            const bool yin = (unsigned)y < (unsigned)Hh;
            const int yc = y < 0 ? 0 : (y > Hh - 1 ? Hh - 1 : y);
            const float* fpl = fb + (size_t)yc * Ww;
            dtile[p][r][xl] = (yin & xin) ? dbp[yc * Ww] : SENT;
            unsigned pk[8];
#pragma unroll
            for (int i = 0; i < 8; ++i)
                pk[i] = packbf(fpl[(size_t)(2 * i) * HW],
                               fpl[(size_t)(2 * i + 1) * HW]);
            unsigned short* wp = &ftile[p][r][xl][0];
            *(uint2v*)(wp)      = (uint2v){pk[0], pk[1]};
            *(uint2v*)(wp + 4)  = (uint2v){pk[2], pk[3]};
            *(uint2v*)(wp + 8)  = (uint2v){pk[4], pk[5]};
            *(uint2v*)(wp + 12) = (uint2v){pk[6], pk[7]};
        }
        // tail px 256,257: 12 threads, one (row, px) pair each
        const int ti = xl - 128;
        if ((unsigned)ti < 12u) {
            const int r  = ti >> 1;
            const int tp = ti & 1;
            const int xt = wstart - 1 + 256 + tp;
            const bool xtin = (unsigned)xt < (unsigned)Ww;
            const int xct = xt > Ww - 1 ? Ww - 1 : xt;
            const int y = h0 - 1 + r;
            const bool yin = (unsigned)y < (unsigned)Hh;
            const int yc = y < 0 ? 0 : (y > Hh - 1 ? Hh - 1 : y);
            const float* fpl = feat + (size_t)b * IC * HW + (size_t)yc * Ww + xct;
            dtile[p][r][256 + tp] = (yin & xtin) ? depth[(b << 18) + yc * Ww + xct]
                                                 : SENT;
            unsigned qk[8];
#pragma unroll
            for (int i = 0; i < 8; ++i)
                qk[i] = packbf(fpl[(size_t)(2 * i) * HW],
                               fpl[(size_t)(2 * i + 1) * HW]);
            unsigned short* wq = &ftile[p][r][256 + tp][0];
            *(uint2v*)(wq)      = (uint2v){qk[0], qk[1]};
            *(uint2v*)(wq + 4)  = (uint2v){qk[2], qk[3]};
            *(uint2v*)(wq + 8)  = (uint2v){qk[4], qk[5]};
            *(uint2v*)(wq + 12) = (uint2v){qk[6], qk[7]};
        }
    };

    // ---- consumer: compute tile tt from buf p ----
    auto compute = [&](int p, int tt) {
        const int b      = tt >> 8;
        const int h0     = ((tt >> 1) & 127) * TR;
        const int wstart = (tt & 1) * TW;
        const int h = h0 + rr;
        float* opb0 = out + ((size_t)(b * OC + oc0) << 18) + (size_t)h * Ww;
#pragma unroll 1
        for (int it = 0; it < 8; ++it) {
            const int xb = xoff + it * 16 + n;
            const int dc = dtile[p][rr + 1][xb + 1];
            float4v acc0 = {0.f, 0.f, 0.f, 0.f};
            float4v acc1 = {0.f, 0.f, 0.f, 0.f};
#pragma unroll
            for (int t = 0; t < 9; ++t) {
                const int kh = t / 3, kw = t % 3;
                unsigned mm;
                if (t == 4) {
                    mm = 0xffff0000u;   // center: diff==0 always, kd=1 slice
                } else {
                    const int diff = dtile[p][rr + kh][xb + kw] - dc;
                    mm = (diff == 0) ? 0xffff0000u : ((diff == -1) ? 0x0000ffffu : 0u);
                }
                const uint2v pr = *(const uint2v*)(&ftile[p][rr + kh][xb + kw][g << 2]);
                union { short8 s; unsigned u[4]; } bf;
                bf.u[0] = __builtin_amdgcn_perm(0u, pr.x, 0x01000100u) & mm;  // ic 4g+0
                bf.u[1] = __builtin_amdgcn_perm(0u, pr.x, 0x03020302u) & mm;  // ic 4g+1
                bf.u[2] = __builtin_amdgcn_perm(0u, pr.y, 0x01000100u) & mm;  // ic 4g+2
                bf.u[3] = __builtin_amdgcn_perm(0u, pr.y, 0x03020302u) & mm;  // ic 4g+3

                // features as A (M=pixels), weights as B (N=oc)
                acc0 = __builtin_amdgcn_mfma_f32_16x16x32_bf16(bf.s, wfrag[t][0], acc0, 0, 0, 0);
                acc1 = __builtin_amdgcn_mfma_f32_16x16x32_bf16(bf.s, wfrag[t][1], acc1, 0, 0, 0);
            }
            // lane stores px w16+4q..+3 of plane oc0 (acc0) / oc0+16 (acc1)
            const int w16 = wstart + xoff + it * 16;
            float* op = opb0 + (w16 + 4 * q);
            *(float4v*)op                     = acc0;
            *(float4v*)(op + (size_t)16 * HW) = acc1;
        }
    };

    // ---- pipelined main loop: producers one tile ahead of consumers ----
    if (isProd) stage(0, t0);
    __syncthreads();
#pragma unroll 1
    for (int i = 0; i < NT; ++i) {
        if (!isProd) {
            compute(i & 1, t0 + i);
        } else if (i + 1 < NT) {
            stage((i + 1) & 1, t0 + i + 1);
        }
        __syncthreads();
    }
}

extern "C" void kernel_launch(void* const* d_in, const int* in_sizes, int n_in,
                              void* d_out, int out_size, void* d_ws, size_t ws_size,
                              hipStream_t stream) {
    const float* feat  = (const float*)d_in[0];
    const int*   depth = (const int*)d_in[1];
    const float* wgt   = (const float*)d_in[2];
    float* out = (float*)d_out;

    unsigned short* wsA = (unsigned short*)d_ws;     // 18,432 B only

    prep_weights<<<36, 256, 0, stream>>>(wgt, wsA);
    depconv_fused<<<256, 768, 0, stream>>>(feat, depth, wsA, out);
}